// Round 1
// baseline (296.642 us; speedup 1.0000x reference)
//
#include <hip/hip_runtime.h>

// y = x @ W^T + bias;  x:[65536,512] f32, W:[512,512] f32 (row = out feature),
// bias:[512] f32, y:[65536,512] f32. Computed in bf16 MFMA (16x16x32), fp32
// accumulate. 128x128 block tile, BK=64, 4 waves (2x2 of 64x64), 4x4 MFMA
// subtiles per wave. fp32->bf16 conversion fused into LDS staging.

#define BM 128
#define BN 128
#define BK 64
#define ABK 72  // LDS leading dim (bf16 elems): 144 B row stride = 36 banks -> <=2-way conflicts (free)

typedef __bf16 bf16x8 __attribute__((ext_vector_type(8)));
typedef float f32x4 __attribute__((ext_vector_type(4)));

__global__ __launch_bounds__(256, 2)
void linear_bf16_mfma(const float* __restrict__ X,
                      const float* __restrict__ W,
                      const float* __restrict__ bias,
                      float* __restrict__ Y) {
  constexpr int K = 512;
  constexpr int N = 512;

  __shared__ __bf16 As[BM * ABK];
  __shared__ __bf16 Bs[BN * ABK];

  const int tid  = threadIdx.x;
  const int lane = tid & 63;
  const int wave = tid >> 6;
  const int bm = blockIdx.y * BM;
  const int bn = blockIdx.x * BN;
  const int wm = (wave >> 1) * 64;  // wave's 64x64 quadrant
  const int wn = (wave & 1) * 64;

  // staging: thread t covers row (t>>3) + 32p, k-cols (t&7)*8 .. +7
  const int srow = tid >> 3;       // 0..31
  const int scol = (tid & 7) * 8;  // 0,8,...,56

  // MFMA A/B fragment addressing: row = lane&15, k = (lane>>4)*8 + j
  const int mrow = lane & 15;
  const int kq   = (lane >> 4) * 8;

  f32x4 acc[4][4] = {};

  for (int k0 = 0; k0 < K; k0 += BK) {
#pragma unroll
    for (int p = 0; p < 4; ++p) {
      const int r = p * 32 + srow;
      const float* ga = X + (size_t)(bm + r) * K + (k0 + scol);
      f32x4 a0 = *(const f32x4*)ga;
      f32x4 a1 = *(const f32x4*)(ga + 4);
      const float* gb = W + (size_t)(bn + r) * K + (k0 + scol);
      f32x4 b0 = *(const f32x4*)gb;
      f32x4 b1 = *(const f32x4*)(gb + 4);
      bf16x8 av, bv;
#pragma unroll
      for (int e = 0; e < 4; ++e) {
        av[e]     = (__bf16)a0[e];
        av[e + 4] = (__bf16)a1[e];
        bv[e]     = (__bf16)b0[e];
        bv[e + 4] = (__bf16)b1[e];
      }
      *(bf16x8*)(&As[r * ABK + scol]) = av;  // 16B aligned: 144r + 2*scol
      *(bf16x8*)(&Bs[r * ABK + scol]) = bv;
    }
    __syncthreads();

#pragma unroll
    for (int ks = 0; ks < BK; ks += 32) {
      bf16x8 af[4], bfr[4];
#pragma unroll
      for (int i = 0; i < 4; ++i)
        af[i] = *(const bf16x8*)(&As[(wm + i * 16 + mrow) * ABK + ks + kq]);
#pragma unroll
      for (int j = 0; j < 4; ++j)
        bfr[j] = *(const bf16x8*)(&Bs[(wn + j * 16 + mrow) * ABK + ks + kq]);
#pragma unroll
      for (int i = 0; i < 4; ++i)
#pragma unroll
        for (int j = 0; j < 4; ++j)
          acc[i][j] = __builtin_amdgcn_mfma_f32_16x16x32_bf16(af[i], bfr[j],
                                                              acc[i][j], 0, 0, 0);
    }
    __syncthreads();
  }

  // epilogue: C/D layout col=lane&15 (n), row=(lane>>4)*4+reg (m)
  const int col0 = lane & 15;
  const int row0 = (lane >> 4) * 4;
#pragma unroll
  for (int j = 0; j < 4; ++j) {
    const int gc = bn + wn + j * 16 + col0;
    const float bj = bias[gc];
#pragma unroll
    for (int i = 0; i < 4; ++i) {
      const int gr = bm + wm + i * 16 + row0;
#pragma unroll
      for (int r = 0; r < 4; ++r)
        Y[(size_t)(gr + r) * N + gc] = acc[i][j][r] + bj;
    }
  }
}

extern "C" void kernel_launch(void* const* d_in, const int* in_sizes, int n_in,
                              void* d_out, int out_size, void* d_ws, size_t ws_size,
                              hipStream_t stream) {
  const float* X = (const float*)d_in[0];   // [65536, 512]
  const float* W = (const float*)d_in[1];   // [512, 512]
  const float* b = (const float*)d_in[2];   // [512]
  float* Y = (float*)d_out;                 // [65536, 512]
  dim3 grid(512 / BN, 65536 / BM);          // (4, 512); x-fastest -> A-tile L2 reuse
  linear_bf16_mfma<<<grid, 256, 0, stream>>>(X, W, b, Y);
}

// Round 2
// 277.403 us; speedup vs baseline: 1.0694x; 1.0694x over previous
//
#include <hip/hip_runtime.h>

// y = x @ W^T + bias; x:[65536,512] f32, W:[512,512] f32, bias:[512] f32.
// bf16 MFMA 16x16x32, fp32 accumulate. 128x128 tile, BK=64, 4 waves.
// R2: XCD swizzle (X-tile sharers -> same XCD L2), register-prefetch
// pipeline (global latency overlaps MFMA), nontemporal Y stores.

#define BM 128
#define BN 128
#define BK 64
#define ABK 72  // 144 B row stride = 36 banks -> <=2-way conflicts (free per m136)

typedef __bf16 bf16x8 __attribute__((ext_vector_type(8)));
typedef float f32x4 __attribute__((ext_vector_type(4)));

__global__ __launch_bounds__(256, 2)
void linear_bf16_mfma(const float* __restrict__ X,
                      const float* __restrict__ W,
                      const float* __restrict__ bias,
                      float* __restrict__ Y) {
  constexpr int K = 512;
  constexpr int N = 512;

  __shared__ __bf16 As[BM * ABK];
  __shared__ __bf16 Bs[BN * ABK];

  const int tid  = threadIdx.x;
  const int lane = tid & 63;
  const int wave = tid >> 6;

  // XCD-locality swizzle: the 4 blocks sharing one X row-tile get linear ids
  // differing by 8 -> same XCD under round-robin dispatch -> X re-reads are
  // L2 hits instead of HBM re-fetches.
  const int lid = blockIdx.x;          // 0..2047
  const int xcd = lid & 7;
  const int ii  = lid >> 3;            // 0..255
  const int nt  = ii & 3;
  const int mt  = (ii >> 2) * 8 + xcd; // 0..511
  const int bm = mt * BM;
  const int bn = nt * BN;

  const int wm = (wave >> 1) * 64;
  const int wn = (wave & 1) * 64;

  // staging: thread t -> row (t>>3)+32p, k-cols (t&7)*8..+7 (32 B contiguous)
  const int srow = tid >> 3;
  const int scol = (tid & 7) * 8;

  // MFMA A/B fragment: row = lane&15, k = (lane>>4)*8 + j
  const int mrow = lane & 15;
  const int kq   = (lane >> 4) * 8;

  const float* Xp = X + (size_t)(bm + srow) * K + scol;
  const float* Wp = W + (size_t)(bn + srow) * K + scol;

  // prefetch tile 0 into registers
  f32x4 xa[4][2], wb[4][2];
#pragma unroll
  for (int p = 0; p < 4; ++p) {
    const float* ga = Xp + (size_t)p * 32 * K;
    xa[p][0] = *(const f32x4*)ga;
    xa[p][1] = *(const f32x4*)(ga + 4);
    const float* gb = Wp + (size_t)p * 32 * K;
    wb[p][0] = *(const f32x4*)gb;
    wb[p][1] = *(const f32x4*)(gb + 4);
  }

  f32x4 acc[4][4] = {};

  for (int k0 = 0; k0 < K; k0 += BK) {
    // convert regs (tile k) -> LDS
#pragma unroll
    for (int p = 0; p < 4; ++p) {
      bf16x8 av, bv;
#pragma unroll
      for (int e = 0; e < 4; ++e) {
        av[e]     = (__bf16)xa[p][0][e];
        av[e + 4] = (__bf16)xa[p][1][e];
        bv[e]     = (__bf16)wb[p][0][e];
        bv[e + 4] = (__bf16)wb[p][1][e];
      }
      const int r = p * 32 + srow;
      *(bf16x8*)(&As[r * ABK + scol]) = av;
      *(bf16x8*)(&Bs[r * ABK + scol]) = bv;
    }
    __syncthreads();

    // issue tile k+1 loads now; ~900-cyc HBM latency overlaps the MFMAs below
    if (k0 + BK < K) {
      const float* Xn = Xp + (k0 + BK);
      const float* Wn = Wp + (k0 + BK);
#pragma unroll
      for (int p = 0; p < 4; ++p) {
        const float* ga = Xn + (size_t)p * 32 * K;
        xa[p][0] = *(const f32x4*)ga;
        xa[p][1] = *(const f32x4*)(ga + 4);
        const float* gb = Wn + (size_t)p * 32 * K;
        wb[p][0] = *(const f32x4*)gb;
        wb[p][1] = *(const f32x4*)(gb + 4);
      }
    }

#pragma unroll
    for (int ks = 0; ks < BK; ks += 32) {
      bf16x8 af[4], bfr[4];
#pragma unroll
      for (int i2 = 0; i2 < 4; ++i2)
        af[i2] = *(const bf16x8*)(&As[(wm + i2 * 16 + mrow) * ABK + ks + kq]);
#pragma unroll
      for (int j = 0; j < 4; ++j)
        bfr[j] = *(const bf16x8*)(&Bs[(wn + j * 16 + mrow) * ABK + ks + kq]);
#pragma unroll
      for (int i2 = 0; i2 < 4; ++i2)
#pragma unroll
        for (int j = 0; j < 4; ++j)
          acc[i2][j] = __builtin_amdgcn_mfma_f32_16x16x32_bf16(af[i2], bfr[j],
                                                               acc[i2][j], 0, 0, 0);
    }
    __syncthreads();
  }

  // epilogue: C/D layout col=lane&15 (n), row=(lane>>4)*4+reg (m)
  const int col0 = lane & 15;
  const int row0 = (lane >> 4) * 4;
#pragma unroll
  for (int j = 0; j < 4; ++j) {
    const int gc = bn + wn + j * 16 + col0;
    const float bj = bias[gc];
#pragma unroll
    for (int i2 = 0; i2 < 4; ++i2) {
      const int gr = bm + wm + i2 * 16 + row0;
#pragma unroll
      for (int r = 0; r < 4; ++r)
        __builtin_nontemporal_store(acc[i2][j][r] + bj,
                                    &Y[(size_t)(gr + r) * N + gc]);
    }
  }
}

extern "C" void kernel_launch(void* const* d_in, const int* in_sizes, int n_in,
                              void* d_out, int out_size, void* d_ws, size_t ws_size,
                              hipStream_t stream) {
  const float* X = (const float*)d_in[0];
  const float* W = (const float*)d_in[1];
  const float* b = (const float*)d_in[2];
  float* Y = (float*)d_out;
  linear_bf16_mfma<<<dim3(2048), 256, 0, stream>>>(X, W, b, Y);
}